// Round 2
// baseline (61.236 us; speedup 1.0000x reference)
//
#include <hip/hip_runtime.h>
#include <float.h>

#define OPH 7
#define OPW 7
#define NC 64
#define NH 50
#define NW 50
#define PLANE (NH * NW)        // 2500
#define OUT_PER_ROI (NC * OPH * OPW)  // 3136
#define BLK 1024
#define LSTRIDE 65             // 64 + 1 pad: avoid bank aliasing across channels

__global__ void __launch_bounds__(BLK)
roi_pool_kernel(const float* __restrict__ x,
                const int* __restrict__ rois,
                float* __restrict__ out) {
    int m = blockIdx.x;
    const int* r = rois + m * 5;
    int b  = r[0];
    // 0.0625 = 2^-4 exact in fp32; coords <= 799 so product exact; trunc == floor
    int x0 = (int)((float)r[1] * 0.0625f);
    int y0 = (int)((float)r[2] * 0.0625f);
    int x1 = (int)((float)r[3] * 0.0625f);
    int y1 = (int)((float)r[4] * 0.0625f);
    int h = y1 - y0 + 1;       // 1..8
    int w = x1 - x0 + 1;       // 1..8

    __shared__ float lds[NC * LSTRIDE];

    const float* xb = x + (size_t)b * NC * PLANE;

    // Stage crop: 64 channels x (<=8 x <=8). Padded to 8x8 slots; lanes outside
    // the crop are predicated off (their LDS slots are never read).
    for (int e = threadIdx.x; e < NC * 64; e += BLK) {
        int c  = e >> 6;
        int p  = e & 63;
        int yy = p >> 3;
        int xx = p & 7;
        if (yy < h && xx < w)
            lds[c * LSTRIDE + p] = xb[c * PLANE + (y0 + yy) * NW + (x0 + xx)];
    }
    __syncthreads();

    // Compute 64*49 outputs from LDS; writes fully coalesced.
    float* ob = out + (size_t)m * OUT_PER_ROI;
    for (int o = threadIdx.x; o < OUT_PER_ROI; o += BLK) {
        int c  = o / (OPH * OPW);          // const divisor -> magic mul
        int p  = o - c * (OPH * OPW);
        int ph = p / OPW;
        int pw = p - ph * OPW;

        int ys = (ph * h) / OPH;
        int ye = ((ph + 1) * h + OPH - 1) / OPH;
        int xs = (pw * w) / OPW;
        int xe = ((pw + 1) * w + OPW - 1) / OPW;

        const float* lc = lds + c * LSTRIDE;
        float mx = -FLT_MAX;
        for (int yy = ys; yy < ye; ++yy)
            for (int xx = xs; xx < xe; ++xx)
                mx = fmaxf(mx, lc[yy * 8 + xx]);
        ob[o] = mx;
    }
}

extern "C" void kernel_launch(void* const* d_in, const int* in_sizes, int n_in,
                              void* d_out, int out_size, void* d_ws, size_t ws_size,
                              hipStream_t stream) {
    const float* x    = (const float*)d_in[0];
    const int*   rois = (const int*)d_in[1];
    float*       out  = (float*)d_out;

    int n_rois = in_sizes[1] / 5;   // 256
    roi_pool_kernel<<<n_rois, BLK, 0, stream>>>(x, rois, out);
}